// Round 4
// baseline (473.724 us; speedup 1.0000x reference)
//
#include <hip/hip_runtime.h>

// PostNormBoth R3: 256 blocks x 256 threads (4 waves), 2 batch rows/block.
// - W_update bf16 A-frags in VGPRs (wfa[4][8] = 128 VGPRs), 64 MFMA/row/step.
// - Fused tanh+LN-partial stats in MFMA epilogue -> 2 barriers/step.
// - Attention weights in regs + rare wave-uniform branch (no s_wt table).
// - Sliding-window register memory (5 slots/row), LDS layouts <=2-way banks.

#define TT 256

typedef __bf16 bf16x8 __attribute__((ext_vector_type(8)));
typedef float  f32x4  __attribute__((ext_vector_type(4)));

__device__ __forceinline__ float fast_tanh(float x) {
    float e = __expf(2.f * x);
    return 1.f - __fdividef(2.f, e + 1.f);
}

template<int CTRL, int RM>
__device__ __forceinline__ float dpp_add(float v) {
    int t = __builtin_amdgcn_update_dpp(0, __float_as_int(v), CTRL, RM, 0xf, true);
    return v + __int_as_float(t);
}
// full 64-lane sum; valid in lane 63 (epilogue only)
__device__ __forceinline__ float wave_sum63(float v) {
    v = dpp_add<0xB1,  0xf>(v);
    v = dpp_add<0x4E,  0xf>(v);
    v = dpp_add<0x141, 0xf>(v);
    v = dpp_add<0x140, 0xf>(v);
    v = dpp_add<0x142, 0xa>(v);
    v = dpp_add<0x143, 0xc>(v);
    return v;
}

// gaussian-attention weights for wave-uniform pointer p (TAU=8, K=2, SLOTS=64)
__device__ __forceinline__ void attn_w(int p, float w[5]) {
    float s = 0.f;
    #pragma unroll
    for (int k = 0; k < 5; ++k) {
        int idx = (p + k - 2) & 63;
        float d = (float)(idx - p);
        w[k] = expf(-(d * d) * 0.125f);
        s += w[k];
    }
    float inv = 1.f / s;
    #pragma unroll
    for (int k = 0; k < 5; ++k) w[k] *= inv;
}

// ---- dynamic LDS layout (bytes) ----
// s_mem [2][64][256] f32 :      0 (131072)
// s_yt  [2][256]     f32 : 131072 (2048)
// s_x   [2][256]     f32 : 133120 (2048)
// s_v   [2][256]    bf16 : 135168 (1024)   row stride 256 -> 2-way banks (free)
// s_red1[2][4]       f32 : 136192 (32)
// s_red2[2][4]       f32 : 136224 (32)
// s_part[4][2][10]   f32 : 136256 (320)
#define SMEM_BYTES 136576

__global__ __launch_bounds__(256, 1)
void postnorm_kernel(const float* __restrict__ x,
                     const float* __restrict__ W_embed,
                     const float* __restrict__ b_embed,
                     const float* __restrict__ W_update,
                     const float* __restrict__ b_update,
                     const float* __restrict__ gamma,
                     const float* __restrict__ beta,
                     const float* __restrict__ W_out,
                     const float* __restrict__ b_out,
                     const float* __restrict__ ctx_s,
                     float* __restrict__ out)
{
    extern __shared__ __align__(16) char smem[];
    float*  s_mem  = (float*)(smem);
    float*  s_yt   = (float*)(smem + 131072);
    float*  s_x    = (float*)(smem + 133120);
    __bf16* s_v    = (__bf16*)(smem + 135168);
    float*  s_red1 = (float*)(smem + 136192);
    float*  s_red2 = (float*)(smem + 136224);
    float*  s_part = (float*)(smem + 136256);

    const int tid  = threadIdx.x;   // role i = tid (handles rows 0 and 1)
    const int i    = tid;
    const int w    = tid >> 6;      // wave 0..3, owns W rows [64w, 64w+64)
    const int lane = tid & 63;
    const int bn   = lane & 15;     // MFMA col; rows real for bn<2
    const int quad = lane >> 4;
    const int r0   = blockIdx.x * 2;

    // ---- init ----
    {   f32x4 z = {0.f, 0.f, 0.f, 0.f};
        f32x4* p = (f32x4*)s_mem;
        #pragma unroll
        for (int k = 0; k < 32; ++k) p[tid + k * 256] = z;
    }
    s_x[i]       = x[r0 * TT + i];
    s_x[256 + i] = x[(r0 + 1) * TT + i];

    const float we  = W_embed[i];
    const float be  = b_embed[i];
    const float gm  = gamma[i];
    const float btt = beta[i];
    const float cs  = 1.f / (1.f + expf(-ctx_s[0]));

    float Wi[5], wt[5];
    attn_w(30, Wi);     // interior weights (p in [2,61] all identical)
    attn_w(0,  wt);     // weights for t=0 (pointer 0, edge case)

    f32x4 bu4[4];
    #pragma unroll
    for (int mt = 0; mt < 4; ++mt)
        bu4[mt] = *(const f32x4*)(b_update + w * 64 + mt * 16 + quad * 4);

    // ---- W_update rows [64w..64w+64) -> bf16 A-frags in regs ----
    bf16x8 wfa[4][8];
    #pragma unroll
    for (int mt = 0; mt < 4; ++mt) {
        #pragma unroll
        for (int kt = 0; kt < 8; ++kt) {
            const float* wp = W_update + (w * 64 + mt * 16 + bn) * 256
                                       + kt * 32 + quad * 8;
            f32x4 a = *(const f32x4*)wp;
            f32x4 b = *(const f32x4*)(wp + 4);
            bf16x8 f;
            f[0] = (__bf16)a[0]; f[1] = (__bf16)a[1];
            f[2] = (__bf16)a[2]; f[3] = (__bf16)a[3];
            f[4] = (__bf16)b[0]; f[5] = (__bf16)b[1];
            f[6] = (__bf16)b[2]; f[7] = (__bf16)b[3];
            wfa[mt][kt] = f;
        }
    }

    __syncthreads();
    {   // v(0): memory==0, h==0 -> v = inp(0)
        float x00 = s_x[0], x01 = s_x[256];     // broadcast reads
        s_v[i]       = (__bf16)fast_tanh(x00 * we + be);
        s_v[256 + i] = (__bf16)fast_tanh(x01 * we + be);
    }
    __syncthreads();

    float hn0 = 0.f, hn1 = 0.f;
    float a0=0,a1=0,a2=0,a3=0,a4=0;   // row0 window: slots t-2..t+2
    float c0=0,c1=0,c2=0,c3=0,c4=0;   // row1 window
    const __bf16* vsrc = s_v + (bn & 1) * 256 + quad * 8;

    #pragma unroll 1
    for (int t = 0; t < TT; ++t) {
        const int tn = (t < TT - 1) ? t + 1 : TT - 1;
        // --- prefetches (cover under MFMA) ---
        float adm0 = s_mem[(((t + 3) & 63) << 8) + i];
        float adm1 = s_mem[16384 + (((t + 3) & 63) << 8) + i];
        float xn0  = s_x[tn];
        float xn1  = s_x[256 + tn];
        float nw0, nw1, nw2, nw3, nw4;
        {   int pn = tn & 63;                    // wave-uniform
            if (pn >= 2 && pn <= 61) {
                nw0 = Wi[0]; nw1 = Wi[1]; nw2 = Wi[2]; nw3 = Wi[3]; nw4 = Wi[4];
            } else {
                float tmp[5]; attn_w(pn, tmp);
                nw0 = tmp[0]; nw1 = tmp[1]; nw2 = tmp[2]; nw3 = tmp[3]; nw4 = tmp[4];
            }
        }

        // --- phase1: MFMA (4 indep chains) + fused tanh/stats ---
        f32x4 acc0 = {0,0,0,0}, acc1 = {0,0,0,0}, acc2 = {0,0,0,0}, acc3 = {0,0,0,0};
        #pragma unroll
        for (int kt = 0; kt < 8; ++kt) {
            bf16x8 bfr = *(const bf16x8*)(vsrc + kt * 32);
            acc0 = __builtin_amdgcn_mfma_f32_16x16x32_bf16(wfa[0][kt], bfr, acc0, 0, 0, 0);
            acc1 = __builtin_amdgcn_mfma_f32_16x16x32_bf16(wfa[1][kt], bfr, acc1, 0, 0, 0);
            acc2 = __builtin_amdgcn_mfma_f32_16x16x32_bf16(wfa[2][kt], bfr, acc2, 0, 0, 0);
            acc3 = __builtin_amdgcn_mfma_f32_16x16x32_bf16(wfa[3][kt], bfr, acc3, 0, 0, 0);
        }
        f32x4 y0, y1, y2, y3;
        float s1 = 0.f, s2 = 0.f;
        #pragma unroll
        for (int e = 0; e < 4; ++e) {
            y0[e] = fast_tanh(acc0[e] + bu4[0][e]);
            y1[e] = fast_tanh(acc1[e] + bu4[1][e]);
            y2[e] = fast_tanh(acc2[e] + bu4[2][e]);
            y3[e] = fast_tanh(acc3[e] + bu4[3][e]);
            s1 += (y0[e] + y1[e]) + (y2[e] + y3[e]);
            s2 += (y0[e]*y0[e] + y1[e]*y1[e]) + (y2[e]*y2[e] + y3[e]*y3[e]);
        }
        // sum over quads (lanes stride 16; preserves bn)
        s1 += __shfl_xor(s1, 16, 64); s1 += __shfl_xor(s1, 32, 64);
        s2 += __shfl_xor(s2, 16, 64); s2 += __shfl_xor(s2, 32, 64);
        if (quad == 0 && bn < 2) { s_red1[bn*4 + w] = s1; s_red2[bn*4 + w] = s2; }
        if (bn < 2) {
            float* yb = s_yt + bn * 256 + w * 64 + quad * 4;
            *(f32x4*)(yb)      = y0;
            *(f32x4*)(yb + 16) = y1;
            *(f32x4*)(yb + 32) = y2;
            *(f32x4*)(yb + 48) = y3;
        }
        __syncthreads();

        // --- phase2: LN finalize + window scatter/gather + v(t+1) ---
        f32x4 q1a = *(const f32x4*)(s_red1);        // broadcast
        f32x4 q1b = *(const f32x4*)(s_red1 + 4);
        f32x4 q2a = *(const f32x4*)(s_red2);
        f32x4 q2b = *(const f32x4*)(s_red2 + 4);
        float yt0 = s_yt[i];
        float yt1 = s_yt[256 + i];
        float S1a = (q1a[0]+q1a[1]) + (q1a[2]+q1a[3]);
        float S2a = (q2a[0]+q2a[1]) + (q2a[2]+q2a[3]);
        float S1b = (q1b[0]+q1b[1]) + (q1b[2]+q1b[3]);
        float S2b = (q2b[0]+q2b[1]) + (q2b[2]+q2b[3]);
        float mu0 = S1a * (1.f/256.f);
        float mu1 = S1b * (1.f/256.f);
        float rs0 = rsqrtf(S2a * (1.f/256.f) - mu0*mu0 + 1e-5f);
        float rs1 = rsqrtf(S2b * (1.f/256.f) - mu1*mu1 + 1e-5f);
        hn0 = (yt0 - mu0) * rs0 * gm + btt;
        hn1 = (yt1 - mu1) * rs1 * gm + btt;

        a0 += wt[0]*hn0; a1 += wt[1]*hn0; a2 += wt[2]*hn0; a3 += wt[3]*hn0; a4 += wt[4]*hn0;
        c0 += wt[0]*hn1; c1 += wt[1]*hn1; c2 += wt[2]*hn1; c3 += wt[3]*hn1; c4 += wt[4]*hn1;

        if (t < TT - 1) {
            const int ret = ((t - 2) & 63) << 8;
            s_mem[ret + i]         = a0;           // retire slot t-2
            s_mem[16384 + ret + i] = c0;
            a0=a1; a1=a2; a2=a3; a3=a4; a4=adm0;
            c0=c1; c1=c2; c2=c3; c3=c4; c4=adm1;
            float ctx0 = ((nw0*a0 + nw1*a1) + (nw2*a2 + nw3*a3)) + nw4*a4;
            float ctx1 = ((nw0*c0 + nw1*c1) + (nw2*c2 + nw3*c3)) + nw4*c4;
            float v0 = fast_tanh(xn0 * we + be) + cs * ctx0 + hn0;
            float v1 = fast_tanh(xn1 * we + be) + cs * ctx1 + hn1;
            s_v[i]       = (__bf16)v0;
            s_v[256 + i] = (__bf16)v1;
            wt[0]=nw0; wt[1]=nw1; wt[2]=nw2; wt[3]=nw3; wt[4]=nw4;
        }
        __syncthreads();
    }

    // --- epilogue: out[r0+n, o] = h_n . W_out[o,:] + b_out[o] ---
    #pragma unroll
    for (int o = 0; o < 10; ++o) {
        float wo = W_out[o * 256 + i];
        float p0 = wave_sum63(hn0 * wo);
        float p1 = wave_sum63(hn1 * wo);
        if (lane == 63) {
            s_part[(w*2 + 0)*10 + o] = p0;
            s_part[(w*2 + 1)*10 + o] = p1;
        }
    }
    __syncthreads();
    if (tid < 20) {
        int n = tid / 10, o = tid % 10;
        float r = b_out[o];
        #pragma unroll
        for (int ww = 0; ww < 4; ++ww) r += s_part[(ww*2 + n)*10 + o];
        out[(r0 + n)*10 + o] = r;
    }
}

extern "C" void kernel_launch(void* const* d_in, const int* in_sizes, int n_in,
                              void* d_out, int out_size, void* d_ws, size_t ws_size,
                              hipStream_t stream) {
    const float* x    = (const float*)d_in[0];
    const float* W_e  = (const float*)d_in[1];
    const float* b_e  = (const float*)d_in[2];
    const float* W_u  = (const float*)d_in[3];
    const float* b_u  = (const float*)d_in[4];
    const float* gmm  = (const float*)d_in[5];
    const float* bta  = (const float*)d_in[6];
    const float* W_o  = (const float*)d_in[7];
    const float* b_o  = (const float*)d_in[8];
    const float* cst  = (const float*)d_in[9];
    float* out = (float*)d_out;

    (void)hipFuncSetAttribute(reinterpret_cast<const void*>(postnorm_kernel),
                              hipFuncAttributeMaxDynamicSharedMemorySize,
                              SMEM_BYTES);

    postnorm_kernel<<<dim3(256), dim3(256), SMEM_BYTES, stream>>>(
        x, W_e, b_e, W_u, b_u, gmm, bta, W_o, b_o, cst, out);
}

// Round 5
// 453.584 us; speedup vs baseline: 1.0444x; 1.0444x over previous
//
#include <hip/hip_runtime.h>

// PostNormBoth R4 = R1 shape + R3 improvements.
// 256 blocks x 512 threads (8 waves, 2 waves/SIMD), 2 batch rows/block.
// - W_update bf16 A-frags in VGPRs (wfa[2][8] = 64 VGPRs/lane).
// - Fused tanh+LN-partials in MFMA epilogue -> 2 barriers/step.
// - Attention weights in registers (wave-uniform branch, no table).
// - s_v row stride 256 (2-way banks = free). Sliding-window reg memory.

#define TT 256

typedef __bf16 bf16x8 __attribute__((ext_vector_type(8)));
typedef float  f32x4  __attribute__((ext_vector_type(4)));

__device__ __forceinline__ float fast_tanh(float x) {
    float e = __expf(2.f * x);
    return 1.f - __fdividef(2.f, e + 1.f);
}

template<int CTRL, int RM>
__device__ __forceinline__ float dpp_add(float v) {
    int t = __builtin_amdgcn_update_dpp(0, __float_as_int(v), CTRL, RM, 0xf, true);
    return v + __int_as_float(t);
}
// full 64-lane sum; valid in lane 63 (used once, in the output epilogue)
__device__ __forceinline__ float wave_sum63(float v) {
    v = dpp_add<0xB1,  0xf>(v);
    v = dpp_add<0x4E,  0xf>(v);
    v = dpp_add<0x141, 0xf>(v);
    v = dpp_add<0x140, 0xf>(v);
    v = dpp_add<0x142, 0xa>(v);
    v = dpp_add<0x143, 0xc>(v);
    return v;
}

// gaussian-attention weights for wave-uniform pointer p (TAU=8, K=2, SLOTS=64)
__device__ __forceinline__ void attn_w(int p, float w[5]) {
    float s = 0.f;
    #pragma unroll
    for (int k = 0; k < 5; ++k) {
        int idx = (p + k - 2) & 63;
        float d = (float)(idx - p);
        w[k] = expf(-(d * d) * 0.125f);
        s += w[k];
    }
    float inv = 1.f / s;
    #pragma unroll
    for (int k = 0; k < 5; ++k) w[k] *= inv;
}

// ---- dynamic LDS layout (bytes) ----
// s_mem [2][64][256] f32 :      0 (131072)
// s_yt  [2][256]     f32 : 131072 (2048)
// s_x   [2][256]     f32 : 133120 (2048)
// s_v   [2][256]    bf16 : 135168 (1024)
// s_red1[2][8]       f32 : 136192 (64)
// s_red2[2][8]       f32 : 136256 (64)
// s_oacc[20]         f32 : 136320 (80)
#define SMEM_BYTES 136400

__global__ __launch_bounds__(512, 2)
void postnorm_kernel(const float* __restrict__ x,
                     const float* __restrict__ W_embed,
                     const float* __restrict__ b_embed,
                     const float* __restrict__ W_update,
                     const float* __restrict__ b_update,
                     const float* __restrict__ gamma,
                     const float* __restrict__ beta,
                     const float* __restrict__ W_out,
                     const float* __restrict__ b_out,
                     const float* __restrict__ ctx_s,
                     float* __restrict__ out)
{
    extern __shared__ __align__(16) char smem[];
    float*  s_mem  = (float*)(smem);
    float*  s_yt   = (float*)(smem + 131072);
    float*  s_x    = (float*)(smem + 133120);
    __bf16* s_v    = (__bf16*)(smem + 135168);
    float*  s_red1 = (float*)(smem + 136192);
    float*  s_red2 = (float*)(smem + 136256);
    float*  s_oacc = (float*)(smem + 136320);

    const int tid  = threadIdx.x;   // 0..511
    const int n    = tid >> 8;      // batch row within block (thread role)
    const int i    = tid & 255;     // hidden index (thread role)
    const int w    = tid >> 6;      // wave 0..7, owns W rows [32w, 32w+32)
    const int lane = tid & 63;
    const int bn   = lane & 15;     // MFMA col; col parity selects row
    const int quad = lane >> 4;
    const int r0   = blockIdx.x * 2;

    // ---- init ----
    {   f32x4 z = {0.f, 0.f, 0.f, 0.f};
        f32x4* p = (f32x4*)s_mem;
        #pragma unroll
        for (int k = 0; k < 16; ++k) p[tid + k * 512] = z;
    }
    s_x[tid] = x[(r0 + n) * TT + i];
    if (tid < 20) s_oacc[tid] = 0.f;

    const float we  = W_embed[i];
    const float be  = b_embed[i];
    const float gm  = gamma[i];
    const float btt = beta[i];
    const float cs  = 1.f / (1.f + expf(-ctx_s[0]));

    float Wi[5];
    attn_w(30, Wi);                       // interior (p in [2,61] identical)
    float wt0, wt1, wt2, wt3, wt4;
    {   float t0[5]; attn_w(0, t0);       // pointer 0 (edge) for t=0
        wt0 = t0[0]; wt1 = t0[1]; wt2 = t0[2]; wt3 = t0[3]; wt4 = t0[4];
    }

    // bias fragments for this lane's two m-tiles (rows w*32+mt*16+quad*4+e)
    const f32x4 bu0 = *(const f32x4*)(b_update + w * 32 + quad * 4);
    const f32x4 bu1 = *(const f32x4*)(b_update + w * 32 + 16 + quad * 4);

    // ---- W_update rows [32w..32w+32) -> bf16 A-frags in regs ----
    bf16x8 wfa[2][8];
    #pragma unroll
    for (int mt = 0; mt < 2; ++mt) {
        #pragma unroll
        for (int kt = 0; kt < 8; ++kt) {
            const float* wp = W_update + (w * 32 + mt * 16 + bn) * 256
                                       + kt * 32 + quad * 8;
            f32x4 a = *(const f32x4*)wp;
            f32x4 b = *(const f32x4*)(wp + 4);
            bf16x8 f;
            f[0] = (__bf16)a[0]; f[1] = (__bf16)a[1];
            f[2] = (__bf16)a[2]; f[3] = (__bf16)a[3];
            f[4] = (__bf16)b[0]; f[5] = (__bf16)b[1];
            f[6] = (__bf16)b[2]; f[7] = (__bf16)b[3];
            wfa[mt][kt] = f;
        }
    }

    __syncthreads();
    {   // v(0): memory==0, h==0 -> v = inp(0)
        float inp = fast_tanh(s_x[n << 8] * we + be);   // s_x[n*256+0] bcast
        s_v[tid] = (__bf16)inp;
    }
    __syncthreads();

    float hn = 0.f;
    float w0 = 0.f, w1 = 0.f, w2 = 0.f, w3 = 0.f, w4 = 0.f; // slots t-2..t+2
    float* mcol = s_mem + (n << 14) + i;
    const __bf16* vsrc = s_v + (bn & 1) * 256 + quad * 8;   // col parity = row

    #pragma unroll 1
    for (int t = 0; t < TT; ++t) {
        const int tn = (t < TT - 1) ? t + 1 : TT - 1;
        // --- prefetches (thread role; cover under MFMA) ---
        float adm = mcol[((t + 3) & 63) << 8];
        float xn  = s_x[(n << 8) + tn];
        float nw0, nw1, nw2, nw3, nw4;
        {   int pn = tn & 63;                    // wave-uniform
            if (pn >= 2 && pn <= 61) {
                nw0 = Wi[0]; nw1 = Wi[1]; nw2 = Wi[2]; nw3 = Wi[3]; nw4 = Wi[4];
            } else {
                float tmp[5]; attn_w(pn, tmp);
                nw0 = tmp[0]; nw1 = tmp[1]; nw2 = tmp[2]; nw3 = tmp[3]; nw4 = tmp[4];
            }
        }

        // --- P1: MFMA (2 indep 8-chains) + fused tanh/LN-partials ---
        f32x4 acc0 = {0,0,0,0}, acc1 = {0,0,0,0};
        #pragma unroll
        for (int kt = 0; kt < 8; ++kt) {
            bf16x8 bfr = *(const bf16x8*)(vsrc + kt * 32);
            acc0 = __builtin_amdgcn_mfma_f32_16x16x32_bf16(wfa[0][kt], bfr, acc0, 0, 0, 0);
            acc1 = __builtin_amdgcn_mfma_f32_16x16x32_bf16(wfa[1][kt], bfr, acc1, 0, 0, 0);
        }
        f32x4 y0, y1;
        float s1 = 0.f, s2 = 0.f;
        #pragma unroll
        for (int e = 0; e < 4; ++e) {
            y0[e] = fast_tanh(acc0[e] + bu0[e]);
            y1[e] = fast_tanh(acc1[e] + bu1[e]);
            s1 += y0[e] + y1[e];
            s2 += y0[e]*y0[e] + y1[e]*y1[e];
        }
        const bool act = (bn < 2);
        s1 = act ? s1 : 0.f;
        s2 = act ? s2 : 0.f;
        // reduce over quads (xor 16/32 preserves bn)
        s1 += __shfl_xor(s1, 16, 64); s1 += __shfl_xor(s1, 32, 64);
        s2 += __shfl_xor(s2, 16, 64); s2 += __shfl_xor(s2, 32, 64);
        if (quad == 0 && act) { s_red1[bn*8 + w] = s1; s_red2[bn*8 + w] = s2; }
        if (act) {
            float* yb = s_yt + bn * 256 + w * 32 + quad * 4;
            *(f32x4*)(yb)      = y0;
            *(f32x4*)(yb + 16) = y1;
        }
        __syncthreads();

        // --- P2: LN finalize + window scatter/gather + v(t+1) (thread role) ---
        f32x4 q1a = *(const f32x4*)(s_red1 + n*8);
        f32x4 q1b = *(const f32x4*)(s_red1 + n*8 + 4);
        f32x4 q2a = *(const f32x4*)(s_red2 + n*8);
        f32x4 q2b = *(const f32x4*)(s_red2 + n*8 + 4);
        float yt = s_yt[tid];
        float S1 = ((q1a[0]+q1a[1]) + (q1a[2]+q1a[3]))
                 + ((q1b[0]+q1b[1]) + (q1b[2]+q1b[3]));
        float S2 = ((q2a[0]+q2a[1]) + (q2a[2]+q2a[3]))
                 + ((q2b[0]+q2b[1]) + (q2b[2]+q2b[3]));
        float mu   = S1 * (1.f/256.f);
        float var  = S2 * (1.f/256.f) - mu*mu;
        float rstd = rsqrtf(var + 1e-5f);
        hn = (yt - mu) * rstd * gm + btt;

        w0 += wt0*hn; w1 += wt1*hn; w2 += wt2*hn; w3 += wt3*hn; w4 += wt4*hn;

        if (t < TT - 1) {
            mcol[((t - 2) & 63) << 8] = w0;          // retire slot t-2
            w0 = w1; w1 = w2; w2 = w3; w3 = w4; w4 = adm;
            float ctx = ((nw0*w0 + nw1*w1) + (nw2*w2 + nw3*w3)) + nw4*w4;
            float inp = fast_tanh(xn * we + be);
            float v = inp + cs * ctx + hn;
            s_v[tid] = (__bf16)v;
            wt0 = nw0; wt1 = nw1; wt2 = nw2; wt3 = nw3; wt4 = nw4;
        }
        __syncthreads();
    }

    // --- epilogue: out[r0+n, o] = h_n . W_out[o,:] + b_out[o] ---
    #pragma unroll
    for (int o = 0; o < 10; ++o) {
        float p = wave_sum63(hn * W_out[o * 256 + i]);  // n is wave-uniform
        if (lane == 63) atomicAdd(&s_oacc[n * 10 + o], p);
    }
    __syncthreads();
    if (tid < 20) {
        int nn = tid / 10, o = tid % 10;
        out[(r0 + nn) * 10 + o] = s_oacc[tid] + b_out[o];
    }
}

extern "C" void kernel_launch(void* const* d_in, const int* in_sizes, int n_in,
                              void* d_out, int out_size, void* d_ws, size_t ws_size,
                              hipStream_t stream) {
    const float* x    = (const float*)d_in[0];
    const float* W_e  = (const float*)d_in[1];
    const float* b_e  = (const float*)d_in[2];
    const float* W_u  = (const float*)d_in[3];
    const float* b_u  = (const float*)d_in[4];
    const float* gmm  = (const float*)d_in[5];
    const float* bta  = (const float*)d_in[6];
    const float* W_o  = (const float*)d_in[7];
    const float* b_o  = (const float*)d_in[8];
    const float* cst  = (const float*)d_in[9];
    float* out = (float*)d_out;

    (void)hipFuncSetAttribute(reinterpret_cast<const void*>(postnorm_kernel),
                              hipFuncAttributeMaxDynamicSharedMemorySize,
                              SMEM_BYTES);

    postnorm_kernel<<<dim3(256), dim3(512), SMEM_BYTES, stream>>>(
        x, W_e, b_e, W_u, b_u, gmm, bta, W_o, b_o, cst, out);
}

// Round 6
// 370.911 us; speedup vs baseline: 1.2772x; 1.2229x over previous
//
#include <hip/hip_runtime.h>

// PostNormBoth R5: 512 blocks x 256 threads (4 waves), 1 batch row/block,
// ~67KB LDS -> 2 blocks/CU (two independent barrier domains, 8 waves/CU).
// - W_update bf16 A-frags in regs (wfa[4][8] -> AGPR side of unified file).
// - B-frag: single row, no parity split -> pure broadcast reads, 0 conflicts.
// - tanh strictly 1 per thread per use-site (no discarded transcendentals).
// - Sliding-window register memory; admit<59 is compile-known zero (no init).

#define TT 256

typedef __bf16 bf16x8 __attribute__((ext_vector_type(8)));
typedef float  f32x4  __attribute__((ext_vector_type(4)));

__device__ __forceinline__ float fast_tanh(float x) {
    float e = __expf(2.f * x);
    return 1.f - __fdividef(2.f, e + 1.f);
}

template<int CTRL, int RM>
__device__ __forceinline__ float dpp_add(float v) {
    int t = __builtin_amdgcn_update_dpp(0, __float_as_int(v), CTRL, RM, 0xf, true);
    return v + __int_as_float(t);
}
// full 64-lane sum; valid in lane 63
__device__ __forceinline__ float wave_sum63(float v) {
    v = dpp_add<0xB1,  0xf>(v);   // quad_perm xor1
    v = dpp_add<0x4E,  0xf>(v);   // quad_perm xor2
    v = dpp_add<0x141, 0xf>(v);   // row_half_mirror
    v = dpp_add<0x140, 0xf>(v);   // row_mirror
    v = dpp_add<0x142, 0xa>(v);   // row_bcast15
    v = dpp_add<0x143, 0xc>(v);   // row_bcast31
    return v;
}

// gaussian-attention weights for wave-uniform pointer p (TAU=8, K=2, SLOTS=64)
__device__ __forceinline__ void attn_w(int p, float w[5]) {
    float s = 0.f;
    #pragma unroll
    for (int k = 0; k < 5; ++k) {
        int idx = (p + k - 2) & 63;
        float d = (float)(idx - p);
        w[k] = expf(-(d * d) * 0.125f);
        s += w[k];
    }
    float inv = 1.f / s;
    #pragma unroll
    for (int k = 0; k < 5; ++k) w[k] *= inv;
}

// ---- dynamic LDS layout (bytes) ----
// s_mem [64][256] f32 :     0 (65536)   never needs zero-init (see admit gate)
// s_yt  [256]     f32 : 65536 (1024)
// s_x   [256]     f32 : 66560 (1024)
// s_v   [256]    bf16 : 67584 (512)
// s_red1[4]       f32 : 68096 (16)
// s_red2[4]       f32 : 68112 (16)
// s_part[4][10]   f32 : 68128 (160)
#define SMEM_BYTES 68288

__global__ __launch_bounds__(256, 2)
void postnorm_kernel(const float* __restrict__ x,
                     const float* __restrict__ W_embed,
                     const float* __restrict__ b_embed,
                     const float* __restrict__ W_update,
                     const float* __restrict__ b_update,
                     const float* __restrict__ gamma,
                     const float* __restrict__ beta,
                     const float* __restrict__ W_out,
                     const float* __restrict__ b_out,
                     const float* __restrict__ ctx_s,
                     float* __restrict__ out)
{
    extern __shared__ __align__(16) char smem[];
    float*  s_mem  = (float*)(smem);
    float*  s_yt   = (float*)(smem + 65536);
    float*  s_x    = (float*)(smem + 66560);
    __bf16* s_v    = (__bf16*)(smem + 67584);
    float*  s_red1 = (float*)(smem + 68096);
    float*  s_red2 = (float*)(smem + 68112);
    float*  s_part = (float*)(smem + 68128);

    const int tid  = threadIdx.x;   // 0..255; thread role i = tid
    const int i    = tid;
    const int w    = tid >> 6;      // wave 0..3, owns W rows [64w, 64w+64)
    const int lane = tid & 63;
    const int bn   = lane & 15;     // MFMA col (all cols replicated)
    const int quad = lane >> 4;
    const int r    = blockIdx.x;    // batch row

    s_x[i] = x[r * TT + i];

    const float we  = W_embed[i];
    const float be  = b_embed[i];
    const float bu  = b_update[i];
    const float gm  = gamma[i];
    const float btt = beta[i];
    const float cs  = 1.f / (1.f + expf(-ctx_s[0]));

    float Wi[5];
    attn_w(30, Wi);                       // interior (p in [2,61] identical)
    float wt0, wt1, wt2, wt3, wt4;
    {   float t0[5]; attn_w(0, t0);       // pointer 0 (edge) for t=0
        wt0 = t0[0]; wt1 = t0[1]; wt2 = t0[2]; wt3 = t0[3]; wt4 = t0[4];
    }

    // ---- W_update rows [64w..64w+64) -> bf16 A-frags in regs ----
    bf16x8 wfa[4][8];
    #pragma unroll
    for (int mt = 0; mt < 4; ++mt) {
        #pragma unroll
        for (int kt = 0; kt < 8; ++kt) {
            const float* wp = W_update + (w * 64 + mt * 16 + bn) * 256
                                       + kt * 32 + quad * 8;
            f32x4 a = *(const f32x4*)wp;
            f32x4 b = *(const f32x4*)(wp + 4);
            bf16x8 f;
            f[0] = (__bf16)a[0]; f[1] = (__bf16)a[1];
            f[2] = (__bf16)a[2]; f[3] = (__bf16)a[3];
            f[4] = (__bf16)b[0]; f[5] = (__bf16)b[1];
            f[6] = (__bf16)b[2]; f[7] = (__bf16)b[3];
            wfa[mt][kt] = f;
        }
    }

    __syncthreads();
    {   // v(0): memory==0, h==0 -> v = inp(0); s_x[0] broadcast
        float inp = fast_tanh(s_x[0] * we + be);
        s_v[i] = (__bf16)inp;
    }
    __syncthreads();

    float hn = 0.f;
    float w0 = 0.f, w1 = 0.f, w2 = 0.f, w3 = 0.f, w4 = 0.f; // slots t-2..t+2
    float* mcol = s_mem + i;                 // column i, stride 256 floats
    const __bf16* vsrc = s_v + quad * 8;     // replicated across all 16 cols

    #pragma unroll 1
    for (int t = 0; t < TT; ++t) {
        const int tn = (t < TT - 1) ? t + 1 : TT - 1;
        // --- prefetches (cover under MFMA). Slot (t+3)&63 was last stored at
        // t-59; for t<59 it is untouched-since-start => exactly zero. ---
        float admld = mcol[((t + 3) & 63) << 8];
        float adm   = (t >= 59) ? admld : 0.f;
        float xn    = s_x[tn];
        float nw0, nw1, nw2, nw3, nw4;
        {   int pn = tn & 63;                    // wave-uniform
            if (pn >= 2 && pn <= 61) {
                nw0 = Wi[0]; nw1 = Wi[1]; nw2 = Wi[2]; nw3 = Wi[3]; nw4 = Wi[4];
            } else {
                float tmp[5]; attn_w(pn, tmp);
                nw0 = tmp[0]; nw1 = tmp[1]; nw2 = tmp[2]; nw3 = tmp[3]; nw4 = tmp[4];
            }
        }

        // --- P1: 32 MFMA (4 indep 8-chains); store raw y (bn==0 lanes) ---
        f32x4 a0 = {0,0,0,0}, a1 = {0,0,0,0}, a2 = {0,0,0,0}, a3 = {0,0,0,0};
        #pragma unroll
        for (int kt = 0; kt < 8; ++kt) {
            bf16x8 bfr = *(const bf16x8*)(vsrc + kt * 32);
            a0 = __builtin_amdgcn_mfma_f32_16x16x32_bf16(wfa[0][kt], bfr, a0, 0, 0, 0);
            a1 = __builtin_amdgcn_mfma_f32_16x16x32_bf16(wfa[1][kt], bfr, a1, 0, 0, 0);
            a2 = __builtin_amdgcn_mfma_f32_16x16x32_bf16(wfa[2][kt], bfr, a2, 0, 0, 0);
            a3 = __builtin_amdgcn_mfma_f32_16x16x32_bf16(wfa[3][kt], bfr, a3, 0, 0, 0);
        }
        if (bn == 0) {                 // D: row = quad*4+e, col 0
            float* yb = s_yt + w * 64 + quad * 4;
            *(f32x4*)(yb)      = a0;
            *(f32x4*)(yb + 16) = a1;
            *(f32x4*)(yb + 32) = a2;
            *(f32x4*)(yb + 48) = a3;
        }
        __syncthreads();

        // --- P2: 1 tanh/thread + DPP stats ---
        float yt = fast_tanh(s_yt[i] + bu);
        float s1 = wave_sum63(yt);
        float s2 = wave_sum63(yt * yt);
        if (lane == 63) { s_red1[w] = s1; s_red2[w] = s2; }
        __syncthreads();

        // --- P3: LN finalize + window scatter/gather + v(t+1) ---
        f32x4 q1 = *(const f32x4*)s_red1;      // broadcast
        f32x4 q2 = *(const f32x4*)s_red2;
        float S1 = (q1[0] + q1[1]) + (q1[2] + q1[3]);
        float S2 = (q2[0] + q2[1]) + (q2[2] + q2[3]);
        float mu   = S1 * (1.f / 256.f);
        float var  = S2 * (1.f / 256.f) - mu * mu;
        float rstd = rsqrtf(var + 1e-5f);
        hn = (yt - mu) * rstd * gm + btt;

        w0 += wt0*hn; w1 += wt1*hn; w2 += wt2*hn; w3 += wt3*hn; w4 += wt4*hn;

        if (t < TT - 1) {
            mcol[((t - 2) & 63) << 8] = w0;      // retire slot t-2
            w0 = w1; w1 = w2; w2 = w3; w3 = w4; w4 = adm;
            float ctx = ((nw0*w0 + nw1*w1) + (nw2*w2 + nw3*w3)) + nw4*w4;
            float inp = fast_tanh(xn * we + be);
            float v = inp + cs * ctx + hn;
            s_v[i] = (__bf16)v;
            wt0 = nw0; wt1 = nw1; wt2 = nw2; wt3 = nw3; wt4 = nw4;
        }
        __syncthreads();
    }

    // --- epilogue: out[r, o] = h . W_out[o,:] + b_out[o] ---
    #pragma unroll
    for (int o = 0; o < 10; ++o) {
        float p = wave_sum63(hn * W_out[o * 256 + i]);
        if (lane == 63) s_part[w * 10 + o] = p;
    }
    __syncthreads();
    if (tid < 10) {
        float rr = b_out[tid];
        #pragma unroll
        for (int ww = 0; ww < 4; ++ww) rr += s_part[ww * 10 + tid];
        out[r * 10 + tid] = rr;
    }
}

extern "C" void kernel_launch(void* const* d_in, const int* in_sizes, int n_in,
                              void* d_out, int out_size, void* d_ws, size_t ws_size,
                              hipStream_t stream) {
    const float* x    = (const float*)d_in[0];
    const float* W_e  = (const float*)d_in[1];
    const float* b_e  = (const float*)d_in[2];
    const float* W_u  = (const float*)d_in[3];
    const float* b_u  = (const float*)d_in[4];
    const float* gmm  = (const float*)d_in[5];
    const float* bta  = (const float*)d_in[6];
    const float* W_o  = (const float*)d_in[7];
    const float* b_o  = (const float*)d_in[8];
    const float* cst  = (const float*)d_in[9];
    float* out = (float*)d_out;

    (void)hipFuncSetAttribute(reinterpret_cast<const void*>(postnorm_kernel),
                              hipFuncAttributeMaxDynamicSharedMemorySize,
                              SMEM_BYTES);

    postnorm_kernel<<<dim3(512), dim3(256), SMEM_BYTES, stream>>>(
        x, W_e, b_e, W_u, b_u, gmm, bta, W_o, b_o, cst, out);
}